// Round 1
// baseline (189.077 us; speedup 1.0000x reference)
//
#include <hip/hip_runtime.h>
#include <math.h>

#define D 256
#define BM 8

// ---------------------------------------------------------------------------
// Fused dual GEMM: x0_i = leaky(x0@W1+b1) (only reduced to a1), x0_j stored,
// a1 = x0_i@wa1+ba1, a2 = x0_j@wa2+ba2.
// Block: 256 threads (one output column each), BM rows per block.
// ---------------------------------------------------------------------------
__global__ __launch_bounds__(256) void k_gemm_fused(
    const float* __restrict__ x0,
    const float* __restrict__ W1, const float* __restrict__ b1,
    const float* __restrict__ W2, const float* __restrict__ b2,
    const float* __restrict__ wa1, const float* __restrict__ ba1,
    const float* __restrict__ wa2, const float* __restrict__ ba2,
    float* __restrict__ x0j, float* __restrict__ a1, float* __restrict__ a2,
    int n)
{
    __shared__ float xt[BM][D];
    __shared__ float part[2][4];
    const int d = threadIdx.x;
    const int r0 = blockIdx.x * BM;

    #pragma unroll
    for (int r = 0; r < BM; ++r) {
        int row = r0 + r;
        xt[r][d] = (row < n) ? x0[(size_t)row * D + d] : 0.0f;
    }
    __syncthreads();

    float acc1[BM], acc2[BM];
    const float bb1 = b1[d], bb2 = b2[d];
    #pragma unroll
    for (int r = 0; r < BM; ++r) { acc1[r] = bb1; acc2[r] = bb2; }

    for (int k = 0; k < D; k += 4) {
        float w1v[4], w2v[4];
        #pragma unroll
        for (int i = 0; i < 4; ++i) {
            w1v[i] = W1[(size_t)(k + i) * D + d];
            w2v[i] = W2[(size_t)(k + i) * D + d];
        }
        #pragma unroll
        for (int r = 0; r < BM; ++r) {
            float4 x = *(const float4*)&xt[r][k];  // broadcast read
            acc1[r] += x.x * w1v[0] + x.y * w1v[1] + x.z * w1v[2] + x.w * w1v[3];
            acc2[r] += x.x * w2v[0] + x.y * w2v[1] + x.z * w2v[2] + x.w * w2v[3];
        }
    }

    const float wa1d = wa1[d], wa2d = wa2[d];
    const int lane = d & 63, wave = d >> 6;

    #pragma unroll
    for (int r = 0; r < BM; ++r) {
        int row = r0 + r;
        float v1 = acc1[r]; v1 = (v1 > 0.0f) ? v1 : 0.2f * v1;  // leaky 0.2
        float v2 = acc2[r]; v2 = (v2 > 0.0f) ? v2 : 0.2f * v2;
        if (row < n) x0j[(size_t)row * D + d] = v2;
        float p1 = v1 * wa1d;
        float p2 = v2 * wa2d;
        #pragma unroll
        for (int o = 32; o > 0; o >>= 1) {
            p1 += __shfl_down(p1, o, 64);
            p2 += __shfl_down(p2, o, 64);
        }
        if (lane == 0) { part[0][wave] = p1; part[1][wave] = p2; }
        __syncthreads();
        if (d == 0 && row < n) {
            a1[row] = part[0][0] + part[0][1] + part[0][2] + part[0][3] + ba1[0];
            a2[row] = part[1][0] + part[1][1] + part[1][2] + part[1][3] + ba2[0];
        }
        __syncthreads();
    }
}

// ---------------------------------------------------------------------------
// CSR build
// ---------------------------------------------------------------------------
__global__ void k_deg(const int* __restrict__ rows, int* __restrict__ deg, int e)
{
    int i = blockIdx.x * 256 + threadIdx.x;
    if (i < e) atomicAdd(&deg[rows[i]], 1);
}

// Single-block exclusive scan of deg[0..n-1] -> off[0..n]; also resets
// deg (reused as the bucket cursor) to the exclusive prefix.
__global__ __launch_bounds__(1024) void k_scan(int* __restrict__ deg_cur,
                                               int* __restrict__ off, int n)
{
    __shared__ int buf[1024];
    __shared__ int carry;
    const int t = threadIdx.x;
    if (t == 0) carry = 0;
    __syncthreads();

    for (int base = 0; base < n; base += 1024) {
        int v = (base + t < n) ? deg_cur[base + t] : 0;
        buf[t] = v;
        __syncthreads();
        for (int o = 1; o < 1024; o <<= 1) {
            int add = (t >= o) ? buf[t - o] : 0;
            __syncthreads();
            buf[t] += add;
            __syncthreads();
        }
        int incl = buf[t];
        int excl = carry + incl - v;
        if (base + t < n) {
            off[base + t] = excl;
            deg_cur[base + t] = excl;   // cursor for bucket pass
        }
        __syncthreads();
        if (t == 0) carry += buf[1023];
        __syncthreads();
    }
    if (t == 0) off[n] = carry;
}

__global__ void k_bucket(const int* __restrict__ rows, const int* __restrict__ cols,
                         int* __restrict__ cur, int* __restrict__ perm, int e)
{
    int i = blockIdx.x * 256 + threadIdx.x;
    if (i < e) {
        int r = rows[i];
        int p = atomicAdd(&cur[r], 1);
        perm[p] = cols[i];
    }
}

// ---------------------------------------------------------------------------
// Aggregate: one block per output row. Threads cooperatively compute the
// attention for a chunk of edges, then each thread (one column) accumulates.
// ---------------------------------------------------------------------------
__global__ __launch_bounds__(256) void k_agg(
    const float* __restrict__ x0j, const float* __restrict__ x0,
    const float* __restrict__ a1, const float* __restrict__ a2,
    const int* __restrict__ off, const int* __restrict__ perm,
    float* __restrict__ out, int n)
{
    const int row = blockIdx.x;
    const int d = threadIdx.x;
    const int beg = off[row], end = off[row + 1];
    const float a1v = a1[row];

    __shared__ float satt[256];
    __shared__ int scol[256];

    float acc = x0[(size_t)row * D + d];

    for (int base = beg; base < end; base += 256) {
        int m = end - base; if (m > 256) m = 256;
        if (d < m) {
            int c = perm[base + d];
            scol[d] = c;
            satt[d] = 1.0f / (1.0f + __expf(-(a1v + a2[c])));
        }
        __syncthreads();
        for (int j = 0; j < m; ++j) {
            acc += satt[j] * x0j[(size_t)scol[j] * D + d];
        }
        __syncthreads();
    }
    out[(size_t)row * D + d] = acc;
}

// ---------------------------------------------------------------------------
extern "C" void kernel_launch(void* const* d_in, const int* in_sizes, int n_in,
                              void* d_out, int out_size, void* d_ws, size_t ws_size,
                              hipStream_t stream)
{
    const float* x0  = (const float*)d_in[0];
    const int*   ei  = (const int*)d_in[1];
    const float* W1  = (const float*)d_in[2];
    const float* b1  = (const float*)d_in[3];
    const float* W2  = (const float*)d_in[4];
    const float* b2  = (const float*)d_in[5];
    const float* wa1 = (const float*)d_in[6];
    const float* ba1 = (const float*)d_in[7];
    const float* wa2 = (const float*)d_in[8];
    const float* ba2 = (const float*)d_in[9];
    float* out = (float*)d_out;

    const int n = in_sizes[0] / D;
    const int e = in_sizes[1] / 2;
    const int* rows = ei;
    const int* cols = ei + e;

    char* ws = (char*)d_ws;
    float* x0j = (float*)ws;                              // n*D floats
    float* a1  = (float*)(ws + (size_t)n * D * 4);        // n floats
    float* a2  = a1 + n;                                  // n floats
    int*   cur = (int*)(a2 + n);                          // n ints (deg -> cursor)
    int*   off = cur + n;                                 // n+1 ints
    int*   perm = off + n + 1;                            // e ints

    hipMemsetAsync(cur, 0, (size_t)n * sizeof(int), stream);

    const int gb = (n + BM - 1) / BM;
    k_gemm_fused<<<gb, 256, 0, stream>>>(x0, W1, b1, W2, b2, wa1, ba1, wa2, ba2,
                                         x0j, a1, a2, n);
    k_deg<<<(e + 255) / 256, 256, 0, stream>>>(rows, cur, e);
    k_scan<<<1, 1024, 0, stream>>>(cur, off, n);
    k_bucket<<<(e + 255) / 256, 256, 0, stream>>>(rows, cols, cur, perm, e);
    k_agg<<<n, 256, 0, stream>>>(x0j, x0, a1, a2, off, perm, out, n);
}

// Round 2
// 124.634 us; speedup vs baseline: 1.5171x; 1.5171x over previous
//
#include <hip/hip_runtime.h>
#include <math.h>

#define D 256

typedef float f32x4 __attribute__((ext_vector_type(4)));
typedef short s16x8 __attribute__((ext_vector_type(8)));

static __device__ __forceinline__ unsigned short f2bf(float x) {
    union { float f; unsigned u; } v; v.f = x;
    unsigned r = v.u + 0x7fff + ((v.u >> 16) & 1);   // round-nearest-even
    return (unsigned short)(r >> 16);
}
static __device__ __forceinline__ float bf2f(unsigned short h) {
    union { unsigned u; float f; } v; v.u = ((unsigned)h) << 16;
    return v.f;
}

// ---------------------------------------------------------------------------
// Prep: x0 -> bf16, W1/W2 -> transposed bf16 wt[j][k] (j in [0,512)), and
// degree count for the CSR build. One kernel, three index ranges.
// ---------------------------------------------------------------------------
__global__ __launch_bounds__(256) void k_prep(
    const float* __restrict__ x0, const float* __restrict__ W1,
    const float* __restrict__ W2, const int* __restrict__ rows,
    unsigned short* __restrict__ xb, unsigned short* __restrict__ wt,
    int* __restrict__ cur, int n, int e)
{
    const int i = blockIdx.x * 256 + threadIdx.x;
    const int nx = n * D;
    if (i < nx) xb[i] = f2bf(x0[i]);
    if (i < 2 * D * D) {
        int k = i >> 9;            // i / 512
        int j = i & 511;
        float v = (j < D) ? W1[(size_t)k * D + j] : W2[(size_t)k * D + (j - D)];
        wt[(size_t)j * D + k] = f2bf(v);
    }
    if (i < e) atomicAdd(&cur[rows[i]], 1);
}

// ---------------------------------------------------------------------------
// MFMA GEMM: computes leaky(x0@[W1 W2]+[b1 b2]); writes x0j (bf16, W2 half),
// and a1/a2 = rowdot(leaky, wa1/wa2) via shfl reduce + atomicAdd.
// Block = 256 thr (4 waves); block tile = 32 rows x 512 cols; wave w owns
// cols [128w, 128w+128).  Fragments loaded direct from global (L1/L2).
// mfma_f32_16x16x32_bf16: A lane: row=l&15, k=(l>>4)*8+j (contiguous 8);
//                         B lane: col=l&15, same k;  D: col=l&15, row=(l>>4)*4+r
// ---------------------------------------------------------------------------
__global__ __launch_bounds__(256) void k_mfma(
    const unsigned short* __restrict__ xb, const unsigned short* __restrict__ wt,
    const float* __restrict__ b1, const float* __restrict__ b2,
    const float* __restrict__ wa1, const float* __restrict__ wa2,
    unsigned short* __restrict__ x0j, float* __restrict__ a1,
    float* __restrict__ a2, int n)
{
    const int t = threadIdx.x;
    const int lane = t & 63, w = t >> 6;
    const int rb = blockIdx.x * 32;
    const int cb = w * 128;          // in [0,512)
    const int lr = lane & 15;
    const int kg = lane >> 4;

    f32x4 acc[2][8] = {};

    #pragma unroll
    for (int ks = 0; ks < 8; ++ks) {
        const int k0 = ks * 32 + kg * 8;
        s16x8 af[2], bfr[8];
        #pragma unroll
        for (int rf = 0; rf < 2; ++rf) {
            int row = rb + rf * 16 + lr; if (row >= n) row = n - 1;
            af[rf] = *(const s16x8*)&xb[(size_t)row * D + k0];
        }
        #pragma unroll
        for (int cf = 0; cf < 8; ++cf) {
            int col = cb + cf * 16 + lr;
            bfr[cf] = *(const s16x8*)&wt[(size_t)col * D + k0];
        }
        #pragma unroll
        for (int rf = 0; rf < 2; ++rf)
            #pragma unroll
            for (int cf = 0; cf < 8; ++cf)
                acc[rf][cf] = __builtin_amdgcn_mfma_f32_16x16x32_bf16(
                    af[rf], bfr[cf], acc[rf][cf], 0, 0, 0);
    }

    const bool isW2 = (cb >= D);
    const float* wav  = isW2 ? wa2 : wa1;
    const float* bias = isW2 ? b2  : b1;
    const int crel = cb - (isW2 ? D : 0);

    float rs[2][4] = {};
    #pragma unroll
    for (int rf = 0; rf < 2; ++rf) {
        #pragma unroll
        for (int cf = 0; cf < 8; ++cf) {
            const int col = crel + cf * 16 + lr;
            const float bv = bias[col], wv = wav[col];
            #pragma unroll
            for (int r = 0; r < 4; ++r) {
                float v = acc[rf][cf][r] + bv;
                v = (v > 0.0f) ? v : 0.2f * v;         // leaky 0.2
                const int row = rb + rf * 16 + kg * 4 + r;
                if (isW2 && row < n) x0j[(size_t)row * D + col] = f2bf(v);
                rs[rf][r] += v * wv;
            }
        }
    }
    #pragma unroll
    for (int rf = 0; rf < 2; ++rf)
        #pragma unroll
        for (int r = 0; r < 4; ++r) {
            float s = rs[rf][r];
            s += __shfl_xor(s, 1, 64);
            s += __shfl_xor(s, 2, 64);
            s += __shfl_xor(s, 4, 64);
            s += __shfl_xor(s, 8, 64);
            if (lr == 0) {
                const int row = rb + rf * 16 + kg * 4 + r;
                if (row < n) atomicAdd(isW2 ? &a2[row] : &a1[row], s);
            }
        }
}

// ---------------------------------------------------------------------------
// Exclusive scan (single block, shfl-based; 4 syncthreads per 1024 chunk).
// ---------------------------------------------------------------------------
__global__ __launch_bounds__(1024) void k_scan(int* __restrict__ deg_cur,
                                               int* __restrict__ off, int n)
{
    __shared__ int wsum[16];
    __shared__ int carry_s;
    const int t = threadIdx.x, lane = t & 63, w = t >> 6;
    if (t == 0) carry_s = 0;
    __syncthreads();

    for (int base = 0; base < n; base += 1024) {
        int v = (base + t < n) ? deg_cur[base + t] : 0;
        int s = v;
        #pragma unroll
        for (int o = 1; o < 64; o <<= 1) {
            int u = __shfl_up(s, o, 64);
            if (lane >= o) s += u;
        }
        if (lane == 63) wsum[w] = s;
        __syncthreads();
        if (w == 0) {
            int x = (lane < 16) ? wsum[lane] : 0;
            #pragma unroll
            for (int o = 1; o < 16; o <<= 1) {
                int u = __shfl_up(x, o, 64);
                if (lane >= o) x += u;
            }
            if (lane < 16) wsum[lane] = x;
        }
        __syncthreads();
        const int woff = (w > 0) ? wsum[w - 1] : 0;
        const int incl = s + woff;
        const int excl = carry_s + incl - v;
        if (base + t < n) {
            off[base + t] = excl;
            deg_cur[base + t] = excl;   // cursor for the bucket pass
        }
        __syncthreads();
        if (t == 1023) carry_s += incl;
        __syncthreads();
    }
    if (t == 0) off[n] = carry_s;
}

__global__ void k_bucket(const int* __restrict__ rows, const int* __restrict__ cols,
                         int* __restrict__ cur, int* __restrict__ perm, int e)
{
    int i = blockIdx.x * 256 + threadIdx.x;
    if (i < e) {
        int r = rows[i];
        int p = atomicAdd(&cur[r], 1);
        perm[p] = cols[i];
    }
}

// ---------------------------------------------------------------------------
// Aggregate: one block per row; bf16 gather of x0j.
// ---------------------------------------------------------------------------
__global__ __launch_bounds__(256) void k_agg(
    const unsigned short* __restrict__ x0j, const float* __restrict__ x0,
    const float* __restrict__ a1, const float* __restrict__ a2,
    const float* __restrict__ ba1, const float* __restrict__ ba2,
    const int* __restrict__ off, const int* __restrict__ perm,
    float* __restrict__ out, int n)
{
    const int row = blockIdx.x;
    const int d = threadIdx.x;
    const int beg = off[row], end = off[row + 1];
    const float a1v = a1[row] + ba1[0] + ba2[0];

    __shared__ float satt[256];
    __shared__ int scol[256];

    float acc = x0[(size_t)row * D + d];

    for (int base = beg; base < end; base += 256) {
        int m = end - base; if (m > 256) m = 256;
        if (d < m) {
            int c = perm[base + d];
            scol[d] = c;
            satt[d] = 1.0f / (1.0f + __expf(-(a1v + a2[c])));
        }
        __syncthreads();
        #pragma unroll 4
        for (int j = 0; j < m; ++j) {
            acc += satt[j] * bf2f(x0j[(size_t)scol[j] * D + d]);
        }
        __syncthreads();
    }
    out[(size_t)row * D + d] = acc;
}

// ---------------------------------------------------------------------------
extern "C" void kernel_launch(void* const* d_in, const int* in_sizes, int n_in,
                              void* d_out, int out_size, void* d_ws, size_t ws_size,
                              hipStream_t stream)
{
    const float* x0  = (const float*)d_in[0];
    const int*   ei  = (const int*)d_in[1];
    const float* W1  = (const float*)d_in[2];
    const float* b1  = (const float*)d_in[3];
    const float* W2  = (const float*)d_in[4];
    const float* b2  = (const float*)d_in[5];
    const float* wa1 = (const float*)d_in[6];
    const float* ba1 = (const float*)d_in[7];
    const float* wa2 = (const float*)d_in[8];
    const float* ba2 = (const float*)d_in[9];
    float* out = (float*)d_out;

    const int n = in_sizes[0] / D;
    const int e = in_sizes[1] / 2;
    const int* rows = ei;
    const int* cols = ei + e;

    char* ws = (char*)d_ws;
    unsigned short* xb  = (unsigned short*)ws;                 // n*D bf16
    unsigned short* wt  = xb + (size_t)n * D;                  // 512*256 bf16
    unsigned short* x0j = wt + (size_t)2 * D * D;              // n*D bf16
    float* a1  = (float*)(x0j + (size_t)n * D);                // n f32
    float* a2  = a1 + n;                                       // n f32
    int*   cur = (int*)(a2 + n);                               // n int
    int*   off = cur + n;                                      // n+1 int
    int*   perm = off + n + 1;                                 // e int

    // zero a1, a2, cur in one shot (contiguous)
    hipMemsetAsync(a1, 0, (size_t)(3 * n) * sizeof(float), stream);

    const int nx = n * D;
    k_prep<<<(nx + 255) / 256, 256, 0, stream>>>(x0, W1, W2, rows, xb, wt, cur, n, e);
    k_mfma<<<(n + 31) / 32, 256, 0, stream>>>(xb, wt, b1, b2, wa1, wa2, x0j, a1, a2, n);
    k_scan<<<1, 1024, 0, stream>>>(cur, off, n);
    k_bucket<<<(e + 255) / 256, 256, 0, stream>>>(rows, cols, cur, perm, e);
    k_agg<<<n, 256, 0, stream>>>(x0j, x0, a1, a2, ba1, ba2, off, perm, out, n);
}

// Round 3
// 107.568 us; speedup vs baseline: 1.7577x; 1.1587x over previous
//
#include <hip/hip_runtime.h>
#include <math.h>

#define D 256

typedef float f32x4 __attribute__((ext_vector_type(4)));
typedef short s16x8 __attribute__((ext_vector_type(8)));

static __device__ __forceinline__ unsigned short f2bf(float x) {
    union { float f; unsigned u; } v; v.f = x;
    unsigned r = v.u + 0x7fff + ((v.u >> 16) & 1);   // round-nearest-even
    return (unsigned short)(r >> 16);
}
static __device__ __forceinline__ float bf2f(unsigned short h) {
    union { unsigned u; float f; } v; v.u = ((unsigned)h) << 16;
    return v.f;
}

// ---------------------------------------------------------------------------
// Prep: x0 -> bf16, W1/W2 -> transposed bf16 wt[j][k] (j in [0,512)), and
// zero the degree counters (atomics happen in k_mfma, strictly after).
// ---------------------------------------------------------------------------
__global__ __launch_bounds__(256) void k_prep(
    const float* __restrict__ x0, const float* __restrict__ W1,
    const float* __restrict__ W2,
    unsigned short* __restrict__ xb, unsigned short* __restrict__ wt,
    int* __restrict__ cur, int n)
{
    const int i = blockIdx.x * 256 + threadIdx.x;
    const int nx = n * D;
    if (i < nx) xb[i] = f2bf(x0[i]);
    if (i < 2 * D * D) {
        int k = i >> 9;            // i / 512
        int j = i & 511;
        float v = (j < D) ? W1[(size_t)k * D + j] : W2[(size_t)k * D + (j - D)];
        wt[(size_t)j * D + k] = f2bf(v);
    }
    if (i < n) cur[i] = 0;
}

// ---------------------------------------------------------------------------
// MFMA GEMM: leaky(x0@[W1 W2]+[b1 b2]); writes x0j (bf16, W2 half) and
// a1/a2 via LDS cross-wave reduce (no atomics, no zero-init). Also counts
// edge degrees (grid-stride atomic loop, overlaps the MFMA pipe).
// Block = 256 thr (4 waves); tile = 32 rows x 512 cols; wave w: cols 128w..
// mfma_f32_16x16x32_bf16: A/B lane: row|col=l&15, k=(l>>4)*8+j;
//                         D lane:   col=l&15, row=(l>>4)*4+r
// ---------------------------------------------------------------------------
__global__ __launch_bounds__(256) void k_mfma(
    const unsigned short* __restrict__ xb, const unsigned short* __restrict__ wt,
    const float* __restrict__ b1, const float* __restrict__ b2,
    const float* __restrict__ wa1, const float* __restrict__ wa2,
    const int* __restrict__ rows, int* __restrict__ cur,
    unsigned short* __restrict__ x0j, float* __restrict__ a1,
    float* __restrict__ a2, int n, int e)
{
    const int t = threadIdx.x;
    const int lane = t & 63, w = t >> 6;

    // degree count (overlaps with the GEMM below)
    {
        const int gtid = blockIdx.x * 256 + t;
        const int gsz = gridDim.x * 256;
        for (int i = gtid; i < e; i += gsz) atomicAdd(&cur[rows[i]], 1);
    }

    const int rb = blockIdx.x * 32;
    const int cb = w * 128;          // in [0,512)
    const int lr = lane & 15;
    const int kg = lane >> 4;

    f32x4 acc[2][8] = {};

    #pragma unroll
    for (int ks = 0; ks < 8; ++ks) {
        const int k0 = ks * 32 + kg * 8;
        s16x8 af[2], bfr[8];
        #pragma unroll
        for (int rf = 0; rf < 2; ++rf) {
            int row = rb + rf * 16 + lr; if (row >= n) row = n - 1;
            af[rf] = *(const s16x8*)&xb[(size_t)row * D + k0];
        }
        #pragma unroll
        for (int cf = 0; cf < 8; ++cf) {
            int col = cb + cf * 16 + lr;
            bfr[cf] = *(const s16x8*)&wt[(size_t)col * D + k0];
        }
        #pragma unroll
        for (int rf = 0; rf < 2; ++rf)
            #pragma unroll
            for (int cf = 0; cf < 8; ++cf)
                acc[rf][cf] = __builtin_amdgcn_mfma_f32_16x16x32_bf16(
                    af[rf], bfr[cf], acc[rf][cf], 0, 0, 0);
    }

    const bool isW2 = (cb >= D);
    const float* wav  = isW2 ? wa2 : wa1;
    const float* bias = isW2 ? b2  : b1;
    const int crel = cb - (isW2 ? D : 0);

    float rs[2][4] = {};
    #pragma unroll
    for (int rf = 0; rf < 2; ++rf) {
        #pragma unroll
        for (int cf = 0; cf < 8; ++cf) {
            const int col = crel + cf * 16 + lr;
            const float bv = bias[col], wv = wav[col];
            #pragma unroll
            for (int r = 0; r < 4; ++r) {
                float v = acc[rf][cf][r] + bv;
                v = (v > 0.0f) ? v : 0.2f * v;         // leaky 0.2
                const int row = rb + rf * 16 + kg * 4 + r;
                if (isW2 && row < n) x0j[(size_t)row * D + col] = f2bf(v);
                rs[rf][r] += v * wv;
            }
        }
    }

    __shared__ float part[4][32];
    #pragma unroll
    for (int rf = 0; rf < 2; ++rf)
        #pragma unroll
        for (int r = 0; r < 4; ++r) {
            float s = rs[rf][r];
            s += __shfl_xor(s, 1, 64);
            s += __shfl_xor(s, 2, 64);
            s += __shfl_xor(s, 4, 64);
            s += __shfl_xor(s, 8, 64);
            if (lr == 0) part[w][rf * 16 + kg * 4 + r] = s;
        }
    __syncthreads();
    if (t < 64) {
        const int rib = t & 31;
        const int which = t >> 5;          // 0 -> a1, 1 -> a2
        const int row = rb + rib;
        if (row < n) {
            if (which == 0) a1[row] = part[0][rib] + part[1][rib];
            else            a2[row] = part[2][rib] + part[3][rib];
        }
    }
}

// ---------------------------------------------------------------------------
// Exclusive scan (single block, shfl-based).
// ---------------------------------------------------------------------------
__global__ __launch_bounds__(1024) void k_scan(int* __restrict__ deg_cur,
                                               int* __restrict__ off, int n)
{
    __shared__ int wsum[16];
    __shared__ int carry_s;
    const int t = threadIdx.x, lane = t & 63, w = t >> 6;
    if (t == 0) carry_s = 0;
    __syncthreads();

    for (int base = 0; base < n; base += 1024) {
        int v = (base + t < n) ? deg_cur[base + t] : 0;
        int s = v;
        #pragma unroll
        for (int o = 1; o < 64; o <<= 1) {
            int u = __shfl_up(s, o, 64);
            if (lane >= o) s += u;
        }
        if (lane == 63) wsum[w] = s;
        __syncthreads();
        if (w == 0) {
            int x = (lane < 16) ? wsum[lane] : 0;
            #pragma unroll
            for (int o = 1; o < 16; o <<= 1) {
                int u = __shfl_up(x, o, 64);
                if (lane >= o) x += u;
            }
            if (lane < 16) wsum[lane] = x;
        }
        __syncthreads();
        const int woff = (w > 0) ? wsum[w - 1] : 0;
        const int incl = s + woff;
        const int excl = carry_s + incl - v;
        if (base + t < n) {
            off[base + t] = excl;
            deg_cur[base + t] = excl;   // cursor for the bucket pass
        }
        __syncthreads();
        if (t == 1023) carry_s += incl;
        __syncthreads();
    }
    if (t == 0) off[n] = carry_s;
}

// ---------------------------------------------------------------------------
// Bucket + fused attention: perm[p] = col, patt[p] = sigmoid(a1[r]+a2[c]+b).
// ---------------------------------------------------------------------------
__global__ void k_bucket(const int* __restrict__ rows, const int* __restrict__ cols,
                         const float* __restrict__ a1, const float* __restrict__ a2,
                         const float* __restrict__ ba1, const float* __restrict__ ba2,
                         int* __restrict__ cur, int* __restrict__ perm,
                         float* __restrict__ patt, int e)
{
    int i = blockIdx.x * 256 + threadIdx.x;
    if (i < e) {
        int r = rows[i];
        int c = cols[i];
        int p = atomicAdd(&cur[r], 1);
        perm[p] = c;
        float z = a1[r] + a2[c] + ba1[0] + ba2[0];
        patt[p] = 1.0f / (1.0f + __expf(-z));
    }
}

// ---------------------------------------------------------------------------
// Aggregate: 1 wave per row; ushort4 (8B/lane) gathers; float4 residual.
// ---------------------------------------------------------------------------
__global__ __launch_bounds__(64) void k_agg(
    const unsigned short* __restrict__ x0j, const float* __restrict__ x0,
    const int* __restrict__ off, const int* __restrict__ perm,
    const float* __restrict__ patt, float* __restrict__ out, int n)
{
    const int row = blockIdx.x;
    const int lane = threadIdx.x;
    const int beg = off[row], end = off[row + 1];

    __shared__ float satt[64];
    __shared__ int scol[64];

    f32x4 acc = *(const f32x4*)&x0[(size_t)row * D + lane * 4];

    for (int base = beg; base < end; base += 64) {
        int m = end - base; if (m > 64) m = 64;
        if (lane < m) {
            scol[lane] = perm[base + lane];
            satt[lane] = patt[base + lane];
        }
        __syncthreads();
        #pragma unroll 4
        for (int j = 0; j < m; ++j) {
            const unsigned short* p = &x0j[(size_t)scol[j] * D + lane * 4];
            ushort4 v = *(const ushort4*)p;
            const float a = satt[j];
            acc.x += a * bf2f(v.x);
            acc.y += a * bf2f(v.y);
            acc.z += a * bf2f(v.z);
            acc.w += a * bf2f(v.w);
        }
        __syncthreads();
    }
    *(f32x4*)&out[(size_t)row * D + lane * 4] = acc;
}

// ---------------------------------------------------------------------------
extern "C" void kernel_launch(void* const* d_in, const int* in_sizes, int n_in,
                              void* d_out, int out_size, void* d_ws, size_t ws_size,
                              hipStream_t stream)
{
    const float* x0  = (const float*)d_in[0];
    const int*   ei  = (const int*)d_in[1];
    const float* W1  = (const float*)d_in[2];
    const float* b1  = (const float*)d_in[3];
    const float* W2  = (const float*)d_in[4];
    const float* b2  = (const float*)d_in[5];
    const float* wa1 = (const float*)d_in[6];
    const float* ba1 = (const float*)d_in[7];
    const float* wa2 = (const float*)d_in[8];
    const float* ba2 = (const float*)d_in[9];
    float* out = (float*)d_out;

    const int n = in_sizes[0] / D;
    const int e = in_sizes[1] / 2;
    const int* rows = ei;
    const int* cols = ei + e;

    char* ws = (char*)d_ws;
    unsigned short* xb  = (unsigned short*)ws;                 // n*D bf16
    unsigned short* wt  = xb + (size_t)n * D;                  // 512*256 bf16
    unsigned short* x0j = wt + (size_t)2 * D * D;              // n*D bf16
    float* a1  = (float*)(x0j + (size_t)n * D);                // n f32
    float* a2  = a1 + n;                                       // n f32
    int*   cur = (int*)(a2 + n);                               // n int
    int*   off = cur + n;                                      // n+1 int
    int*   perm = off + n + 1;                                 // e int
    float* patt = (float*)(perm + e);                          // e f32

    const int nx = n * D;
    k_prep<<<(nx + 255) / 256, 256, 0, stream>>>(x0, W1, W2, xb, wt, cur, n);
    k_mfma<<<(n + 31) / 32, 256, 0, stream>>>(xb, wt, b1, b2, wa1, wa2,
                                              rows, cur, x0j, a1, a2, n, e);
    k_scan<<<1, 1024, 0, stream>>>(cur, off, n);
    k_bucket<<<(e + 255) / 256, 256, 0, stream>>>(rows, cols, a1, a2, ba1, ba2,
                                                  cur, perm, patt, e);
    k_agg<<<n, 64, 0, stream>>>(x0j, x0, off, perm, patt, out, n);
}

// Round 4
// 106.996 us; speedup vs baseline: 1.7671x; 1.0053x over previous
//
#include <hip/hip_runtime.h>
#include <math.h>

#define D 256

typedef float f32x4 __attribute__((ext_vector_type(4)));
typedef short s16x8 __attribute__((ext_vector_type(8)));

static __device__ __forceinline__ unsigned short f2bf(float x) {
    union { float f; unsigned u; } v; v.f = x;
    unsigned r = v.u + 0x7fff + ((v.u >> 16) & 1);   // round-nearest-even
    return (unsigned short)(r >> 16);
}
static __device__ __forceinline__ float bf2f(unsigned short h) {
    union { unsigned u; float f; } v; v.u = ((unsigned)h) << 16;
    return v.f;
}

// ---------------------------------------------------------------------------
// Zero a1/a2/cur (contiguous 3n ints). Own kernel: the rocclr fill was 42us.
// ---------------------------------------------------------------------------
__global__ __launch_bounds__(256) void k_zero(int* __restrict__ p, int n3)
{
    int i = blockIdx.x * 256 + threadIdx.x;
    if (i < n3) p[i] = 0;
}

// ---------------------------------------------------------------------------
// Prep: x0 -> bf16 (vectorized x4), W1/W2 -> transposed bf16 wt[j][k]
// (j in [0,512)), degree count (cur zeroed by k_zero).
// ---------------------------------------------------------------------------
__global__ __launch_bounds__(256) void k_prep(
    const float* __restrict__ x0, const float* __restrict__ W1,
    const float* __restrict__ W2, const int* __restrict__ rows,
    unsigned short* __restrict__ xb, unsigned short* __restrict__ wt,
    int* __restrict__ cur, int n, int e)
{
    const int i = blockIdx.x * 256 + threadIdx.x;
    const int nx4 = n * D / 4;
    if (i < nx4) {
        f32x4 v = *(const f32x4*)&x0[(size_t)i * 4];
        ushort4 o;
        o.x = f2bf(v.x); o.y = f2bf(v.y); o.z = f2bf(v.z); o.w = f2bf(v.w);
        *(ushort4*)&xb[(size_t)i * 4] = o;
    }
    if (i < 2 * D * D) {
        int k = i >> 9;            // i / 512
        int j = i & 511;
        float v = (j < D) ? W1[(size_t)k * D + j] : W2[(size_t)k * D + (j - D)];
        wt[(size_t)j * D + k] = f2bf(v);
    }
    if (i < e) atomicAdd(&cur[rows[i]], 1);
}

// ---------------------------------------------------------------------------
// MFMA GEMM: leaky(x0@[W1 W2]+[b1 b2]); x0j (bf16, W2 half); a1/a2 rowdots
// via shfl + LDS + 32 atomicAdd per block (a1/a2 zeroed by k_zero).
// Grid: (n/32) x 4 col-blocks. Block 256 thr (4 waves); wave w owns
// 32 rows x 32 cols: cb = by*128 + w*32. acc[2][2] (16 VGPR).
// mfma_f32_16x16x32_bf16: A/B lane: row|col=l&15, k=(l>>4)*8+j;
//                         D lane:   col=l&15, row=(l>>4)*4+r
// ---------------------------------------------------------------------------
__global__ __launch_bounds__(256) void k_mfma(
    const unsigned short* __restrict__ xb, const unsigned short* __restrict__ wt,
    const float* __restrict__ b1, const float* __restrict__ b2,
    const float* __restrict__ wa1, const float* __restrict__ wa2,
    unsigned short* __restrict__ x0j, float* __restrict__ a1,
    float* __restrict__ a2, int n)
{
    const int t = threadIdx.x;
    const int lane = t & 63, w = t >> 6;
    const int rb = blockIdx.x * 32;
    const int cb = blockIdx.y * 128 + w * 32;    // global col in [0,512)
    const int lr = lane & 15;
    const int kg = lane >> 4;

    f32x4 acc[2][2] = {};

    #pragma unroll
    for (int ks = 0; ks < 8; ++ks) {
        const int k0 = ks * 32 + kg * 8;
        s16x8 af[2], bfr[2];
        #pragma unroll
        for (int rf = 0; rf < 2; ++rf) {
            int row = rb + rf * 16 + lr; if (row >= n) row = n - 1;
            af[rf] = *(const s16x8*)&xb[(size_t)row * D + k0];
        }
        #pragma unroll
        for (int cf = 0; cf < 2; ++cf) {
            int col = cb + cf * 16 + lr;
            bfr[cf] = *(const s16x8*)&wt[(size_t)col * D + k0];
        }
        #pragma unroll
        for (int rf = 0; rf < 2; ++rf)
            #pragma unroll
            for (int cf = 0; cf < 2; ++cf)
                acc[rf][cf] = __builtin_amdgcn_mfma_f32_16x16x32_bf16(
                    af[rf], bfr[cf], acc[rf][cf], 0, 0, 0);
    }

    const bool isW2 = (blockIdx.y >= 2);
    const float* wav  = isW2 ? wa2 : wa1;
    const float* bias = isW2 ? b2  : b1;
    const int crel = cb - (isW2 ? D : 0);        // col within half, [0,256)

    float rs[2][4] = {};
    #pragma unroll
    for (int rf = 0; rf < 2; ++rf) {
        #pragma unroll
        for (int cf = 0; cf < 2; ++cf) {
            const int col = crel + cf * 16 + lr;
            const float bv = bias[col], wv = wav[col];
            #pragma unroll
            for (int r = 0; r < 4; ++r) {
                float v = acc[rf][cf][r] + bv;
                v = (v > 0.0f) ? v : 0.2f * v;           // leaky 0.2
                const int row = rb + rf * 16 + kg * 4 + r;
                if (isW2 && row < n) x0j[(size_t)row * D + col] = f2bf(v);
                rs[rf][r] += v * wv;
            }
        }
    }

    __shared__ float part[4][32];
    #pragma unroll
    for (int rf = 0; rf < 2; ++rf)
        #pragma unroll
        for (int r = 0; r < 4; ++r) {
            float s = rs[rf][r];
            s += __shfl_xor(s, 1, 64);
            s += __shfl_xor(s, 2, 64);
            s += __shfl_xor(s, 4, 64);
            s += __shfl_xor(s, 8, 64);
            if (lr == 0) part[w][rf * 16 + kg * 4 + r] = s;
        }
    __syncthreads();
    if (t < 32) {
        const int row = rb + t;
        if (row < n) {
            float s = part[0][t] + part[1][t] + part[2][t] + part[3][t];
            atomicAdd(isW2 ? &a2[row] : &a1[row], s);
        }
    }
}

// ---------------------------------------------------------------------------
// Exclusive scan (single block, shfl-based).
// ---------------------------------------------------------------------------
__global__ __launch_bounds__(1024) void k_scan(int* __restrict__ deg_cur,
                                               int* __restrict__ off, int n)
{
    __shared__ int wsum[16];
    __shared__ int carry_s;
    const int t = threadIdx.x, lane = t & 63, w = t >> 6;
    if (t == 0) carry_s = 0;
    __syncthreads();

    for (int base = 0; base < n; base += 1024) {
        int v = (base + t < n) ? deg_cur[base + t] : 0;
        int s = v;
        #pragma unroll
        for (int o = 1; o < 64; o <<= 1) {
            int u = __shfl_up(s, o, 64);
            if (lane >= o) s += u;
        }
        if (lane == 63) wsum[w] = s;
        __syncthreads();
        if (w == 0) {
            int x = (lane < 16) ? wsum[lane] : 0;
            #pragma unroll
            for (int o = 1; o < 16; o <<= 1) {
                int u = __shfl_up(x, o, 64);
                if (lane >= o) x += u;
            }
            if (lane < 16) wsum[lane] = x;
        }
        __syncthreads();
        const int woff = (w > 0) ? wsum[w - 1] : 0;
        const int incl = s + woff;
        const int excl = carry_s + incl - v;
        if (base + t < n) {
            off[base + t] = excl;
            deg_cur[base + t] = excl;   // cursor for the bucket pass
        }
        __syncthreads();
        if (t == 1023) carry_s += incl;
        __syncthreads();
    }
    if (t == 0) off[n] = carry_s;
}

// ---------------------------------------------------------------------------
// Bucket + fused attention: perm[p] = col, patt[p] = sigmoid(a1[r]+a2[c]+b).
// ---------------------------------------------------------------------------
__global__ void k_bucket(const int* __restrict__ rows, const int* __restrict__ cols,
                         const float* __restrict__ a1, const float* __restrict__ a2,
                         const float* __restrict__ ba1, const float* __restrict__ ba2,
                         int* __restrict__ cur, int* __restrict__ perm,
                         float* __restrict__ patt, int e)
{
    int i = blockIdx.x * 256 + threadIdx.x;
    if (i < e) {
        int r = rows[i];
        int c = cols[i];
        int p = atomicAdd(&cur[r], 1);
        perm[p] = c;
        float z = a1[r] + a2[c] + ba1[0] + ba2[0];
        patt[p] = 1.0f / (1.0f + __expf(-z));
    }
}

// ---------------------------------------------------------------------------
// Aggregate: 1 wave per row; ushort4 (8B/lane) gathers; float4 residual.
// ---------------------------------------------------------------------------
__global__ __launch_bounds__(64) void k_agg(
    const unsigned short* __restrict__ x0j, const float* __restrict__ x0,
    const int* __restrict__ off, const int* __restrict__ perm,
    const float* __restrict__ patt, float* __restrict__ out, int n)
{
    const int row = blockIdx.x;
    const int lane = threadIdx.x;
    const int beg = off[row], end = off[row + 1];

    __shared__ float satt[64];
    __shared__ int scol[64];

    f32x4 acc = *(const f32x4*)&x0[(size_t)row * D + lane * 4];

    for (int base = beg; base < end; base += 64) {
        int m = end - base; if (m > 64) m = 64;
        if (lane < m) {
            scol[lane] = perm[base + lane];
            satt[lane] = patt[base + lane];
        }
        __syncthreads();
        #pragma unroll 4
        for (int j = 0; j < m; ++j) {
            const unsigned short* p = &x0j[(size_t)scol[j] * D + lane * 4];
            ushort4 v = *(const ushort4*)p;
            const float a = satt[j];
            acc.x += a * bf2f(v.x);
            acc.y += a * bf2f(v.y);
            acc.z += a * bf2f(v.z);
            acc.w += a * bf2f(v.w);
        }
        __syncthreads();
    }
    *(f32x4*)&out[(size_t)row * D + lane * 4] = acc;
}

// ---------------------------------------------------------------------------
extern "C" void kernel_launch(void* const* d_in, const int* in_sizes, int n_in,
                              void* d_out, int out_size, void* d_ws, size_t ws_size,
                              hipStream_t stream)
{
    const float* x0  = (const float*)d_in[0];
    const int*   ei  = (const int*)d_in[1];
    const float* W1  = (const float*)d_in[2];
    const float* b1  = (const float*)d_in[3];
    const float* W2  = (const float*)d_in[4];
    const float* b2  = (const float*)d_in[5];
    const float* wa1 = (const float*)d_in[6];
    const float* ba1 = (const float*)d_in[7];
    const float* wa2 = (const float*)d_in[8];
    const float* ba2 = (const float*)d_in[9];
    float* out = (float*)d_out;

    const int n = in_sizes[0] / D;
    const int e = in_sizes[1] / 2;
    const int* rows = ei;
    const int* cols = ei + e;

    char* ws = (char*)d_ws;
    unsigned short* xb  = (unsigned short*)ws;                 // n*D bf16
    unsigned short* wt  = xb + (size_t)n * D;                  // 512*256 bf16
    unsigned short* x0j = wt + (size_t)2 * D * D;              // n*D bf16
    float* a1  = (float*)(x0j + (size_t)n * D);                // n f32
    float* a2  = a1 + n;                                       // n f32
    int*   cur = (int*)(a2 + n);                               // n int
    int*   off = cur + n;                                      // n+1 int
    int*   perm = off + n + 1;                                 // e int
    float* patt = (float*)(perm + e);                          // e f32

    k_zero<<<(3 * n + 255) / 256, 256, 0, stream>>>((int*)a1, 3 * n);

    const int pthreads = n * D / 4;   // 640k >= max(e, 2*D*D)
    k_prep<<<(pthreads + 255) / 256, 256, 0, stream>>>(x0, W1, W2, rows,
                                                       xb, wt, cur, n, e);
    dim3 mg((n + 31) / 32, 4);
    k_mfma<<<mg, 256, 0, stream>>>(xb, wt, b1, b2, wa1, wa2, x0j, a1, a2, n);
    k_scan<<<1, 1024, 0, stream>>>(cur, off, n);
    k_bucket<<<(e + 255) / 256, 256, 0, stream>>>(rows, cols, a1, a2, ba1, ba2,
                                                  cur, perm, patt, e);
    k_agg<<<n, 64, 0, stream>>>(x0j, x0, off, perm, patt, out, n);
}

// Round 5
// 93.570 us; speedup vs baseline: 2.0207x; 1.1435x over previous
//
#include <hip/hip_runtime.h>
#include <math.h>

#define D 256

typedef float f32x4 __attribute__((ext_vector_type(4)));
typedef short s16x8 __attribute__((ext_vector_type(8)));
typedef unsigned short u16x8 __attribute__((ext_vector_type(8)));

static __device__ __forceinline__ unsigned short f2bf(float x) {
    union { float f; unsigned u; } v; v.f = x;
    unsigned r = v.u + 0x7fff + ((v.u >> 16) & 1);   // round-nearest-even
    return (unsigned short)(r >> 16);
}
static __device__ __forceinline__ float bf2f(unsigned short h) {
    union { unsigned u; float f; } v; v.u = ((unsigned)h) << 16;
    return v.f;
}

// ---------------------------------------------------------------------------
// Prep: x0 -> bf16 (x4 vectorized), W1/W2 -> transposed bf16 wt[j][k]
// (j in [0,512)), zero cur + gtotal. Degree atomics happen later (k_mfma).
// ---------------------------------------------------------------------------
__global__ __launch_bounds__(256) void k_prep(
    const float* __restrict__ x0, const float* __restrict__ W1,
    const float* __restrict__ W2,
    unsigned short* __restrict__ xb, unsigned short* __restrict__ wt,
    int* __restrict__ cur, int* __restrict__ gtotal, int n)
{
    const int i = blockIdx.x * 256 + threadIdx.x;
    const int nx4 = n * D / 4;
    if (i < nx4) {
        f32x4 v = *(const f32x4*)&x0[(size_t)i * 4];
        ushort4 o;
        o.x = f2bf(v.x); o.y = f2bf(v.y); o.z = f2bf(v.z); o.w = f2bf(v.w);
        *(ushort4*)&xb[(size_t)i * 4] = o;
    }
    if (i < 2 * D * D) {
        int k = i >> 9;            // i / 512
        int j = i & 511;
        float v = (j < D) ? W1[(size_t)k * D + j] : W2[(size_t)k * D + (j - D)];
        wt[(size_t)j * D + k] = f2bf(v);
    }
    if (i < n) cur[i] = 0;
    if (i == 0) *gtotal = 0;
}

// ---------------------------------------------------------------------------
// MFMA GEMM: leaky(x0@[W1 W2]+[b1 b2]); x0j (bf16, W2 half); per-block
// 128-col partial rowdots -> pa[by][row] (exclusive, plain store).
// Also one degree atomic per thread (grid covers e).
// Grid: (n/32) x 4. Wave w owns 32 rows x 32 cols, cb = by*128 + w*32.
// mfma_f32_16x16x32_bf16: A/B lane: row|col=l&15, k=(l>>4)*8+j;
//                         D lane:   col=l&15, row=(l>>4)*4+r
// ---------------------------------------------------------------------------
__global__ __launch_bounds__(256) void k_mfma(
    const unsigned short* __restrict__ xb, const unsigned short* __restrict__ wt,
    const float* __restrict__ b1, const float* __restrict__ b2,
    const float* __restrict__ wa1, const float* __restrict__ wa2,
    const int* __restrict__ rows, int* __restrict__ cur,
    unsigned short* __restrict__ x0j, float* __restrict__ pa, int n, int e)
{
    const int t = threadIdx.x;
    const int lane = t & 63, w = t >> 6;

    {   // degree count: exactly one edge per thread (grid covers e)
        const int g = (blockIdx.y * gridDim.x + blockIdx.x) * 256 + t;
        if (g < e) atomicAdd(&cur[rows[g]], 1);
    }

    const int rb = blockIdx.x * 32;
    const int cb = blockIdx.y * 128 + w * 32;    // global col in [0,512)
    const int lr = lane & 15;
    const int kg = lane >> 4;

    f32x4 acc[2][2] = {};

    #pragma unroll
    for (int ks = 0; ks < 8; ++ks) {
        const int k0 = ks * 32 + kg * 8;
        s16x8 af[2], bfr[2];
        #pragma unroll
        for (int rf = 0; rf < 2; ++rf) {
            int row = rb + rf * 16 + lr; if (row >= n) row = n - 1;
            af[rf] = *(const s16x8*)&xb[(size_t)row * D + k0];
        }
        #pragma unroll
        for (int cf = 0; cf < 2; ++cf) {
            int col = cb + cf * 16 + lr;
            bfr[cf] = *(const s16x8*)&wt[(size_t)col * D + k0];
        }
        #pragma unroll
        for (int rf = 0; rf < 2; ++rf)
            #pragma unroll
            for (int cf = 0; cf < 2; ++cf)
                acc[rf][cf] = __builtin_amdgcn_mfma_f32_16x16x32_bf16(
                    af[rf], bfr[cf], acc[rf][cf], 0, 0, 0);
    }

    const bool isW2 = (blockIdx.y >= 2);
    const float* wav  = isW2 ? wa2 : wa1;
    const float* bias = isW2 ? b2  : b1;
    const int crel = cb - (isW2 ? D : 0);        // col within half, [0,256)

    float rs[2][4] = {};
    #pragma unroll
    for (int rf = 0; rf < 2; ++rf) {
        #pragma unroll
        for (int cf = 0; cf < 2; ++cf) {
            const int col = crel + cf * 16 + lr;
            const float bv = bias[col], wv = wav[col];
            #pragma unroll
            for (int r = 0; r < 4; ++r) {
                float v = acc[rf][cf][r] + bv;
                v = (v > 0.0f) ? v : 0.2f * v;           // leaky 0.2
                const int row = rb + rf * 16 + kg * 4 + r;
                if (isW2 && row < n) x0j[(size_t)row * D + col] = f2bf(v);
                rs[rf][r] += v * wv;
            }
        }
    }

    __shared__ float part[4][32];
    #pragma unroll
    for (int rf = 0; rf < 2; ++rf)
        #pragma unroll
        for (int r = 0; r < 4; ++r) {
            float s = rs[rf][r];
            s += __shfl_xor(s, 1, 64);
            s += __shfl_xor(s, 2, 64);
            s += __shfl_xor(s, 4, 64);
            s += __shfl_xor(s, 8, 64);
            if (lr == 0) part[w][rf * 16 + kg * 4 + r] = s;
        }
    __syncthreads();
    if (t < 32) {
        const int row = rb + t;
        if (row < n)
            pa[(size_t)blockIdx.y * n + row] =
                part[0][t] + part[1][t] + part[2][t] + part[3][t];
    }
}

// ---------------------------------------------------------------------------
// Assign: order-free CSR offsets (wave shfl-scan + 1 atomic per wave) and
// a1/a2 finalize from the 4 column-block partials.
// ---------------------------------------------------------------------------
__global__ __launch_bounds__(256) void k_assign(
    int* __restrict__ cur, int* __restrict__ off,
    const float* __restrict__ pa, float* __restrict__ a1,
    float* __restrict__ a2, int* __restrict__ gtotal, int n)
{
    const int i = blockIdx.x * 256 + threadIdx.x;
    const int lane = threadIdx.x & 63;
    int d = (i < n) ? cur[i] : 0;
    int s = d;
    #pragma unroll
    for (int o = 1; o < 64; o <<= 1) {
        int u = __shfl_up(s, o, 64);
        if (lane >= o) s += u;
    }
    int wtot = __shfl(s, 63, 64);
    int base = 0;
    if (lane == 63) base = atomicAdd(gtotal, wtot);
    base = __shfl(base, 63, 64);
    int excl = base + s - d;
    if (i < n) {
        off[i] = excl;
        cur[i] = excl;                       // cursor for bucket pass
        a1[i] = pa[i] + pa[(size_t)n + i];
        a2[i] = pa[(size_t)2 * n + i] + pa[(size_t)3 * n + i];
    }
}

// ---------------------------------------------------------------------------
// Bucket + fused attention: perm[p] = col, patt[p] = sigmoid(a1[r]+a2[c]+b).
// After this, cur[row] == end of row's segment.
// ---------------------------------------------------------------------------
__global__ void k_bucket(const int* __restrict__ rows, const int* __restrict__ cols,
                         const float* __restrict__ a1, const float* __restrict__ a2,
                         const float* __restrict__ ba1, const float* __restrict__ ba2,
                         int* __restrict__ cur, int* __restrict__ perm,
                         float* __restrict__ patt, int e)
{
    int i = blockIdx.x * 256 + threadIdx.x;
    if (i < e) {
        int r = rows[i];
        int c = cols[i];
        int p = atomicAdd(&cur[r], 1);
        perm[p] = c;
        float z = a1[r] + a2[c] + ba1[0] + ba2[0];
        patt[p] = 1.0f / (1.0f + __expf(-z));
    }
}

// ---------------------------------------------------------------------------
// Aggregate: 1 wave per row, TWO edges in flight (half-wave each, ushort8 =
// 16B/lane gathers of the 512B x0j row), shfl_xor(32) combine, f32x4 store.
// ---------------------------------------------------------------------------
__global__ __launch_bounds__(64) void k_agg(
    const unsigned short* __restrict__ x0j, const float* __restrict__ x0,
    const int* __restrict__ off, const int* __restrict__ curend,
    const int* __restrict__ perm, const float* __restrict__ patt,
    float* __restrict__ out, int n)
{
    const int row = blockIdx.x;
    const int lane = threadIdx.x;
    const int half = lane >> 5, hl = lane & 31;
    const int beg = off[row], end = curend[row];

    __shared__ float satt[64];
    __shared__ int scol[64];

    float acc[8] = {0.f, 0.f, 0.f, 0.f, 0.f, 0.f, 0.f, 0.f};

    for (int base = beg; base < end; base += 64) {
        int m = end - base; if (m > 64) m = 64;
        if (lane < m) {
            scol[lane] = perm[base + lane];
            satt[lane] = patt[base + lane];
        }
        __syncthreads();
        for (int j = 0; j < m; j += 2) {
            const int idx = j + half;
            float a = 0.0f; int c = 0;
            if (idx < m) { a = satt[idx]; c = scol[idx]; }
            u16x8 v = *(const u16x8*)&x0j[(size_t)c * D + hl * 8];
            #pragma unroll
            for (int k = 0; k < 8; ++k) acc[k] += a * bf2f(v[k]);
        }
        __syncthreads();
    }

    #pragma unroll
    for (int k = 0; k < 8; ++k) acc[k] += __shfl_xor(acc[k], 32, 64);

    // half h stores cols hl*8 + 4h .. +4 (32B per lane total across halves)
    const int col = hl * 8 + half * 4;
    float s0 = half ? acc[4] : acc[0];
    float s1 = half ? acc[5] : acc[1];
    float s2 = half ? acc[6] : acc[2];
    float s3 = half ? acc[7] : acc[3];
    f32x4 r = *(const f32x4*)&x0[(size_t)row * D + col];
    f32x4 o;
    o.x = r.x + s0; o.y = r.y + s1; o.z = r.z + s2; o.w = r.w + s3;
    *(f32x4*)&out[(size_t)row * D + col] = o;
}

// ---------------------------------------------------------------------------
extern "C" void kernel_launch(void* const* d_in, const int* in_sizes, int n_in,
                              void* d_out, int out_size, void* d_ws, size_t ws_size,
                              hipStream_t stream)
{
    const float* x0  = (const float*)d_in[0];
    const int*   ei  = (const int*)d_in[1];
    const float* W1  = (const float*)d_in[2];
    const float* b1  = (const float*)d_in[3];
    const float* W2  = (const float*)d_in[4];
    const float* b2  = (const float*)d_in[5];
    const float* wa1 = (const float*)d_in[6];
    const float* ba1 = (const float*)d_in[7];
    const float* wa2 = (const float*)d_in[8];
    const float* ba2 = (const float*)d_in[9];
    float* out = (float*)d_out;

    const int n = in_sizes[0] / D;
    const int e = in_sizes[1] / 2;
    const int* rows = ei;
    const int* cols = ei + e;

    char* ws = (char*)d_ws;
    unsigned short* xb  = (unsigned short*)ws;                 // n*D bf16
    unsigned short* wt  = xb + (size_t)n * D;                  // 512*256 bf16
    unsigned short* x0j = wt + (size_t)2 * D * D;              // n*D bf16
    float* pa  = (float*)(x0j + (size_t)n * D);                // 4n f32
    float* a1  = pa + (size_t)4 * n;                           // n f32
    float* a2  = a1 + n;                                       // n f32
    int*   cur = (int*)(a2 + n);                               // n int
    int*   off = cur + n;                                      // n int
    int*   perm = off + n;                                     // e int
    float* patt = (float*)(perm + e);                          // e f32
    int*   gtotal = (int*)(patt + e);                          // 1 int

    const int pthreads = n * D / 4;   // 640k >= max(2*D*D, n)
    k_prep<<<(pthreads + 255) / 256, 256, 0, stream>>>(x0, W1, W2, xb, wt,
                                                       cur, gtotal, n);
    dim3 mg((n + 31) / 32, 4);        // 313*4*256 = 320512 threads >= e
    k_mfma<<<mg, 256, 0, stream>>>(xb, wt, b1, b2, wa1, wa2, rows, cur,
                                   x0j, pa, n, e);
    k_assign<<<(n + 255) / 256, 256, 0, stream>>>(cur, off, pa, a1, a2,
                                                  gtotal, n);
    k_bucket<<<(e + 255) / 256, 256, 0, stream>>>(rows, cols, a1, a2, ba1, ba2,
                                                  cur, perm, patt, e);
    k_agg<<<n, 64, 0, stream>>>(x0j, x0, off, cur, perm, patt, out, n);
}